// Round 14
// baseline (1977.913 us; speedup 1.0000x reference)
//
#include <hip/hip_runtime.h>

#define B_ 256
#define T_ 128
#define F_ 784
#define FP_ 800          // F padded to multiple of 32
#define H_ 1024
#define NG_ 4096         // 4*H
#define C_ 10
#define TC_ 16           // time-chunk length
#define MC_ (B_ * TC_)   // rows per chunk = 4096
#define BN_EPS 1e-3f

typedef short s16x8 __attribute__((ext_vector_type(8)));
typedef float f32x4 __attribute__((ext_vector_type(4)));
typedef unsigned long long u64;

__device__ __forceinline__ ushort f2bf(float f) {
    union { float f; unsigned u; } v; v.f = f;
    unsigned r = v.u + 0x7FFFu + ((v.u >> 16) & 1u);
    return (ushort)(r >> 16);
}
__device__ __forceinline__ float bf2f(ushort h) {
    union { unsigned u; float f; } v; v.u = ((unsigned)h) << 16;
    return v.f;
}
__device__ __forceinline__ float sigm(float x) {
    return 1.0f / (1.0f + __expf(-x));
}
__device__ __forceinline__ float fast_tanh(float x) {
    x = fminf(15.0f, fmaxf(-15.0f, x));
    float e = __expf(2.0f * x);
    return (e - 1.0f) / (e + 1.0f);
}
// async 16B global -> LDS (DMA path, vmcnt-tracked)
__device__ __forceinline__ void gl_lds16(const ushort* g, ushort* l) {
    __builtin_amdgcn_global_load_lds(
        (__attribute__((address_space(1))) void*)(g),
        (__attribute__((address_space(3))) void*)(l), 16, 0, 0);
}

// ---------------- prep: BN scale/shift, W_out^T bf16, zero state, zero barriers ----------
__global__ __launch_bounds__(256) void prep_params(
    const float* __restrict__ gamma1, const float* __restrict__ beta1,
    const float* __restrict__ mean1, const float* __restrict__ var1,
    const float* __restrict__ gamma2, const float* __restrict__ beta2,
    const float* __restrict__ mean2, const float* __restrict__ var2,
    const float* __restrict__ W_out,
    float* __restrict__ sc1, float* __restrict__ sh1,
    float* __restrict__ sc2, float* __restrict__ sh2,
    ushort* __restrict__ woutT, float* __restrict__ c_buf, ushort* __restrict__ h_hist,
    unsigned* __restrict__ bar)
{
    int idx = blockIdx.x * 256 + threadIdx.x;
    if (idx < 1024) bar[idx] = 0u;
    if (idx < B_ * H_) { c_buf[idx] = 0.0f; h_hist[idx] = 0; }  // h slot 0 = h_{-1} = 0
    if (idx < H_) {
        float s1 = gamma1[idx] * rsqrtf(var1[idx] + BN_EPS);
        sc1[idx] = s1; sh1[idx] = beta1[idx] - mean1[idx] * s1;
        float s2 = gamma2[idx] * rsqrtf(var2[idx] + BN_EPS);
        sc2[idx] = s2; sh2[idx] = beta2[idx] - mean2[idx] * s2;
    }
    if (idx < 16 * H_) {
        int n = idx >> 10, k = idx & (H_ - 1);
        woutT[idx] = (n < C_) ? f2bf(W_out[k * C_ + n]) : (ushort)0;
    }
}

// ---------------- generic f32 (K,N) -> bf16 (N,Kpad) transpose, zero-padded ----------------
__global__ __launch_bounds__(256) void transpose_f32_to_bf16(
    const float* __restrict__ src, ushort* __restrict__ dst, int K, int N, int Kpad)
{
    __shared__ float tile[32][33];
    int tx = threadIdx.x & 31, ty = threadIdx.x >> 5;
    int bx = blockIdx.x, by = blockIdx.y;
    int col = bx * 32 + tx;
    for (int l = 0; l < 4; ++l) {
        int row = by * 32 + ty + l * 8;
        tile[ty + l * 8][tx] = (row < K && col < N) ? src[(long)row * N + col] : 0.0f;
    }
    __syncthreads();
    for (int l = 0; l < 4; ++l) {
        int n = bx * 32 + ty + l * 8;
        int k = by * 32 + tx;
        if (n < N && k < Kpad) dst[(long)n * Kpad + k] = f2bf(tile[tx][ty + l * 8]);
    }
}

// ---- same, but output rows gate-packed: src col n = g*H + u  ->  dst row n2 = u*4 + g ----
__global__ __launch_bounds__(256) void transpose_perm_bf16(
    const float* __restrict__ src, ushort* __restrict__ dst)   // K=H_, N=NG_, Kpad=H_
{
    __shared__ float tile[32][33];
    int tx = threadIdx.x & 31, ty = threadIdx.x >> 5;
    int bx = blockIdx.x, by = blockIdx.y;
    int col = bx * 32 + tx;
    for (int l = 0; l < 4; ++l) {
        int row = by * 32 + ty + l * 8;
        tile[ty + l * 8][tx] = (row < H_) ? src[(long)row * NG_ + col] : 0.0f;
    }
    __syncthreads();
    for (int l = 0; l < 4; ++l) {
        int n = bx * 32 + ty + l * 8;       // original col: g*H + u
        int k = by * 32 + tx;
        int n2 = (n & (H_ - 1)) * 4 + (n >> 10);
        dst[(long)n2 * H_ + k] = f2bf(tile[tx][ty + l * 8]);
    }
}

// ---------------- x chunk -> bf16, chunk-row order (tl*B+b), padded K to 800 ----------------
__device__ __forceinline__ void convert_body(
    const float* __restrict__ x, ushort* __restrict__ xbf, int t0, int idx)
{
    int m = idx / 100;
    int kc = idx - m * 100;
    int b = m & (B_ - 1), tl = m >> 8;
    int k = kc * 8;
    ushort o[8];
    if (k < F_) {
        const float* src = x + ((long)b * T_ + t0 + tl) * F_ + k;
        float4 v0 = *(const float4*)src, v1 = *(const float4*)(src + 4);
        o[0]=f2bf(v0.x); o[1]=f2bf(v0.y); o[2]=f2bf(v0.z); o[3]=f2bf(v0.w);
        o[4]=f2bf(v1.x); o[5]=f2bf(v1.y); o[6]=f2bf(v1.z); o[7]=f2bf(v1.w);
    } else {
        for (int i = 0; i < 8; ++i) o[i] = 0;
    }
    *(uint4*)(xbf + (long)m * FP_ + k) = *(uint4*)o;
}

__global__ __launch_bounds__(256) void convert_x(
    const float* __restrict__ x, ushort* __restrict__ xbf, int t0)
{
    convert_body(x, xbf, t0, blockIdx.x * 256 + threadIdx.x);
}

// ---------------- GEMM1 tile body: one 64x128 output tile, 256 threads (ltid) --------------
// v15-proven: 2 blocks/CU class staging via global_load_lds; per-output k-order fixed.
__device__ __forceinline__ void gemm1_tile(
    ushort* As, ushort* Bs, int ltid, int L,
    const ushort* __restrict__ xbf, const ushort* __restrict__ wfeT,
    const float* __restrict__ b_fe, const float* __restrict__ sc1, const float* __restrict__ sh1,
    ushort* __restrict__ feat_c)
{
    int m0 = (L >> 3) * 64;                   // m-tile (64 rows)
    int n0 = (L & 7) * 128;                   // n-tile (128 cols)
    int wave = ltid >> 6, lane = ltid & 63;
    int wm = wave >> 1, wn = wave & 1;        // 2 m-groups (32 rows) x 2 n-groups (64 cols)
    int l15 = lane & 15, quad = lane >> 4;

    f32x4 zero = {0.f, 0.f, 0.f, 0.f};
    f32x4 acc[2][4];
    for (int i = 0; i < 2; i++) for (int j = 0; j < 4; j++) acc[i][j] = zero;

    int srow = lane >> 2, kcol = (lane & 3) * 8;
    for (int kk = 0; kk < FP_ / 32; ++kk) {
        int kb = kk * 32;
        #pragma unroll
        for (int i = 0; i < 3; ++i) {
            int u = wave * 3 + i;                     // 0..11
            int cr = ((u < 4) ? (u << 4) : ((u - 4) << 4)) + srow;
            const ushort* src = (u < 4) ? (xbf  + (long)(m0 + cr) * FP_ + kb + kcol)
                                        : (wfeT + (long)(n0 + cr) * FP_ + kb + kcol);
            ushort* dst = (u < 4) ? (As + (u * 64 + lane) * 8)
                                  : (Bs + ((u - 4) * 64 + lane) * 8);
            gl_lds16(src, dst);
        }
        __syncthreads();
        s16x8 af[2], bfr[4];
        for (int i = 0; i < 2; i++) af[i]  = *(const s16x8*)&As[(wm * 32 + i * 16 + l15) * 32 + quad * 8];
        for (int j = 0; j < 4; j++) bfr[j] = *(const s16x8*)&Bs[(wn * 64 + j * 16 + l15) * 32 + quad * 8];
        for (int i = 0; i < 2; i++)
            for (int j = 0; j < 4; j++)
                acc[i][j] = __builtin_amdgcn_mfma_f32_16x16x32_bf16(af[i], bfr[j], acc[i][j], 0, 0, 0);
        __syncthreads();
    }
    for (int j = 0; j < 4; j++) {
        int n_g = n0 + wn * 64 + j * 16 + l15;
        float bia = b_fe[n_g], s1 = sc1[n_g], sh = sh1[n_g];
        for (int i = 0; i < 2; i++) {
            int mb = m0 + wm * 32 + i * 16 + quad * 4;
            for (int r = 0; r < 4; r++) {
                float v = fast_tanh(acc[i][j][r] + bia);
                v = fast_tanh(v * s1 + sh);
                feat_c[(long)(mb + r) * H_ + n_g] = f2bf(v);
            }
        }
    }
}

// standalone gemm1 (prologue, chunk 0): 512 blocks x 256 thr
__global__ __launch_bounds__(256, 2) void gemm1_c(
    const ushort* __restrict__ xbf, const ushort* __restrict__ wfeT,
    const float* __restrict__ b_fe, const float* __restrict__ sc1, const float* __restrict__ sh1,
    ushort* __restrict__ feat_c)
{
    __shared__ __align__(16) ushort As[64 * 32];
    __shared__ __align__(16) ushort Bs[128 * 32];
    int h = blockIdx.x;
    int L = (h & 7) * 64 + (h >> 3);          // [0,512)
    gemm1_tile(As, Bs, threadIdx.x, L, xbf, wfeT, b_fe, sc1, sh1, feat_c);
}

// ---------------- GEMM2 (per chunk) + fused convert_x(ci+1) -------------------------------
// gemm2 role: blocks 0..1023, supertile/XCD remap (R7-proven). convert role: blocks 1024+.
__global__ __launch_bounds__(256) void gemm2_conv(
    const ushort* __restrict__ feat_c, const ushort* __restrict__ kT2,
    ushort* __restrict__ zx_c,
    const float* __restrict__ x, ushort* __restrict__ xbf, int t0n, int do_conv)
{
    int hb = blockIdx.x;
    int tid = threadIdx.x;
    if (hb >= 1024) {
        if (do_conv)
            convert_body(x, xbf, t0n, (hb - 1024) * 256 + tid);
        return;
    }
    __shared__ __align__(16) ushort As[128 * 32];
    __shared__ __align__(16) ushort Bs[128 * 32];
    int L = (hb & 7) * 128 + (hb >> 3);       // [0,1024)
    int st = L >> 6, s = L & 63;              // st in [0,16)
    int m0 = ((st >> 2) * 8 + (s >> 3)) * 128; // by in [0,32)
    int n0 = ((st & 3) * 8 + (s & 7)) * 128;   // bx in [0,32)
    int wave = tid >> 6, lane = tid & 63;
    int wm = wave >> 1, wn = wave & 1;
    int l15 = lane & 15, quad = lane >> 4;

    f32x4 zero = {0.f, 0.f, 0.f, 0.f};
    f32x4 acc[4][4];
    for (int i = 0; i < 4; i++) for (int j = 0; j < 4; j++) acc[i][j] = zero;

    int srow = lane >> 2, kcol = (lane & 3) * 8;
    for (int kk = 0; kk < H_ / 32; ++kk) {
        int kb = kk * 32;
        #pragma unroll
        for (int i = 0; i < 4; ++i) {
            int c = wave * 4 + i;
            int cr = ((c & 7) << 4) + srow;
            const ushort* src = (c < 8) ? (feat_c + (long)(m0 + cr) * H_ + kb + kcol)
                                        : (kT2   + (long)(n0 + cr) * H_ + kb + kcol);
            ushort* dst = ((c < 8) ? As : Bs) + ((c & 7) << 9) + lane * 8;
            gl_lds16(src, dst);
        }
        __syncthreads();
        s16x8 af[4], bfr[4];
        for (int i = 0; i < 4; i++) af[i]  = *(const s16x8*)&As[(wm * 64 + i * 16 + l15) * 32 + quad * 8];
        for (int j = 0; j < 4; j++) bfr[j] = *(const s16x8*)&Bs[(wn * 64 + j * 16 + l15) * 32 + quad * 8];
        for (int i = 0; i < 4; i++)
            for (int j = 0; j < 4; j++)
                acc[i][j] = __builtin_amdgcn_mfma_f32_16x16x32_bf16(af[i], bfr[j], acc[i][j], 0, 0, 0);
        __syncthreads();
    }
    for (int j = 0; j < 4; j++) {
        int n_g = n0 + wn * 64 + j * 16 + l15;
        for (int i = 0; i < 4; i++) {
            int mb = m0 + wm * 64 + i * 16 + quad * 4;
            for (int r = 0; r < 4; r++)
                zx_c[(long)(mb + r) * NG_ + n_g] = f2bf(acc[i][j][r]);
        }
    }
}

// ------------- fused: LSTM v11 (blocks 0..255) + gemm1(ci+1) (blocks 256..511) -------------
// lstm v11 (R8-proven, 123 us): eighth-domains, 512 thr, 8 waves, 4x8KB ping-pong, waits
// {3,2,2,2,2,2,1,0}, refill depth 3, rfrag in regs, XCD-local h + flag sync. LDS 49664 B.
// gemm1 role: 512 threads = TWO independent 256-thr halves, each one 64x128 tile. Both
// halves execute identical barrier counts -> block-wide __syncthreads stays in lockstep.
// LDS union: lstm 49664 B vs gemm1 2x12288 B -> 49664 B/block => 3 blocks/CU capacity =>
// all 512 blocks resident (512 < 768) regardless of placement; lstm flag sync safe.
// Dependencies via stream order: conv(ci+1) [gemm2_conv(ci)] -> gemm1(ci+1) [here] ->
// gemm2(ci+1) [next dispatch]. feat_c written here, read next dispatch. All bodies proven.
__global__ __launch_bounds__(512, 2) void lstm_g1(
    ushort* __restrict__ h_hist, float* __restrict__ c_buf,
    const ushort* __restrict__ rT2, const ushort* __restrict__ zx_c,
    const float* __restrict__ bias, const float* __restrict__ pi,
    const float* __restrict__ pf, const float* __restrict__ po,
    unsigned* __restrict__ bar, int ci,
    const ushort* __restrict__ xbf, const ushort* __restrict__ wfeT,
    const float* __restrict__ b_fe, const float* __restrict__ sc1g,
    const float* __restrict__ sh1g, ushort* __restrict__ feat_c, int do_g1)
{
    __shared__ __align__(16) char smem[49664];
    int tid = threadIdx.x;

    if (blockIdx.x >= 256) {
        if (do_g1) {
            int b = blockIdx.x - 256;                 // 0..255
            int s = tid >> 8, ltid = tid & 255;       // two halves
            int L = (b & 7) * 64 + (b >> 3) * 2 + s;  // bijective onto [0,512)
            ushort* As = (ushort*)(smem + s * 12288);
            ushort* Bs = (ushort*)(smem + s * 12288 + 4096);
            gemm1_tile(As, Bs, ltid, L, xbf, wfeT, b_fe, sc1g, sh1g, feat_c);
        }
        return;
    }

    ushort* HbBase = (ushort*)smem;                   // 4 x 4096 ushorts (8KB each)
    float*  zb     = (float*)(smem + 32768);          // [128][33] floats
    int dom = blockIdx.x & 7;            // batch-domain: rows dom*32 .. (one XCD)
    int nb  = blockIdx.x >> 3;           // 0..31 unit-block
    int ub  = nb * 32;                   // first hidden unit owned (32 units)
    int m0  = dom * 32;
    unsigned* flags  = bar + dom * 8 * 16;                 // 8 lines, 64B apart
    unsigned* myFlag = bar + (dom * 8 + (nb >> 2)) * 16;

    int wave = tid >> 6, lane = tid & 63;
    int wn = wave;                        // 8 n-groups (16 gate-cols each)
    int l15 = lane & 15, quad = lane >> 4;

    int b2 = tid & 31, seg = tid >> 5;   // cell identity: local row b2, units seg*2..seg*2+1
    int gr = m0 + b2;                    // global batch row
    float cst[2];
    *(float2*)cst = *(const float2*)(c_buf + (long)gr * H_ + ub + seg * 2);
    float bi2[2], bff[2], bc2[2], bo2[2], pI[2], pF[2], pO[2];
    for (int u = 0; u < 2; ++u) {
        int ug = ub + seg * 2 + u;
        bi2[u] = bias[ug];          bff[u] = bias[H_ + ug];
        bc2[u] = bias[2 * H_ + ug]; bo2[u] = bias[3 * H_ + ug];
        pI[u] = pi[ug]; pF[u] = pf[ug]; pO[u] = po[ug];
    }

    // R strip fragments -> registers (once per chunk). 128 VGPRs.
    s16x8 rfrag[32];
    {
        const ushort* rbase = rT2 + (long)(ub * 4 + wn * 16 + l15) * H_ + quad * 8;
        #pragma unroll
        for (int kk = 0; kk < 32; ++kk)
            rfrag[kk] = *(const s16x8*)(rbase + kk * 32);
    }

    // staging: per eighth, 1 DMA/thread. granule G=tid: row=G>>4 (0..31), colg=G&15.
    // Source colg pre-swizzled ^ (row&7) (XOR involution, de-applied on read).
    int srcoff, ldsoff;
    {
        int sr = tid >> 4;                            // 0..31
        int sc = (tid & 15) ^ (sr & 7);
        srcoff = sr * H_ + sc * 8;                    // ushort offset; + e*128 per eighth
        ldsoff = tid * 8;
    }

    // MFMA-read geometry: de-swizzle on read with the same XOR
    int r0 = l15;
    int rx = l15 & 7;                                 // (r0+16)&7 == rx
    asm volatile("s_waitcnt vmcnt(0)" ::: "memory");
    __syncthreads();

    for (int tl = 0; tl < TC_; ++tl) {
        int SG = ci * TC_ + tl;
        const ushort* hsrc = h_hist +
            (size_t)((tl == 0) ? (ci == 0 ? 0 : TC_) : tl) * (B_ * H_) + (size_t)m0 * H_;
        const ushort* zr = zx_c + ((size_t)tl * B_ + gr) * NG_ + (ub + seg * 2) * 4;
        union { uint4 u4; ushort s[8]; } zv;

        // prologue issue order (pinned): zx first, then E0..E3 (1 instr each)
        zv.u4 = *(const uint4*)zr;
        __builtin_amdgcn_sched_barrier(0);
        #pragma unroll
        for (int eq = 0; eq < 4; ++eq) {
            gl_lds16(hsrc + srcoff + eq * 128, HbBase + eq * 4096 + ldsoff);
            __builtin_amdgcn_sched_barrier(0);
        }

        f32x4 acc0 = {0.f, 0.f, 0.f, 0.f}, acc1 = {0.f, 0.f, 0.f, 0.f};

        // segment e: wait(Ne)+barrier ; [refill E(e+3) for e=1..4] ; MFMA eighth e
#define SEG(E, VN, REFILL) \
        asm volatile("s_waitcnt vmcnt(" #VN ") lgkmcnt(0)\n\ts_barrier" ::: "memory"); \
        __builtin_amdgcn_sched_barrier(0); \
        if (REFILL) { \
            gl_lds16(hsrc + srcoff + ((E) + 3) * 128, HbBase + (((E) - 1) & 3) * 4096 + ldsoff); \
        } \
        { \
            const ushort* bp = HbBase + ((E) & 3) * 4096; \
            _Pragma("unroll") \
            for (int kkl = 0; kkl < 4; ++kkl) { \
                s16x8 bfr = rfrag[(E) * 4 + kkl]; \
                int po_ = ((kkl * 4 + quad) ^ rx) << 3; \
                s16x8 a0v = *(const s16x8*)(bp + r0 * 128 + po_); \
                s16x8 a1v = *(const s16x8*)(bp + (r0 + 16) * 128 + po_); \
                acc0 = __builtin_amdgcn_mfma_f32_16x16x32_bf16(a0v, bfr, acc0, 0, 0, 0); \
                acc1 = __builtin_amdgcn_mfma_f32_16x16x32_bf16(a1v, bfr, acc1, 0, 0, 0); \
            } \
        }

        SEG(0, 3, 0)
        SEG(1, 2, 1)
        SEG(2, 2, 1)
        SEG(3, 2, 1)
        SEG(4, 2, 1)
        SEG(5, 2, 0)
        SEG(6, 1, 0)
        SEG(7, 0, 0)
#undef SEG

        // z -> LDS, col-major: zb[gatecol][row] stride 33
        #pragma unroll
        for (int r = 0; r < 4; ++r)
            zb[(wn * 16 + l15) * 33 + quad * 4 + r] = acc0[r];
        #pragma unroll
        for (int r = 0; r < 4; ++r)
            zb[(wn * 16 + l15) * 33 + 16 + quad * 4 + r] = acc1[r];
        __syncthreads();

        // cell update: 2 units/thread; zx gate-packed -> one contiguous 16B read
        ushort hnew[2];
        #pragma unroll
        for (int u = 0; u < 2; ++u) {
            int cb2 = (seg * 2 + u) * 4;
            float zi = zb[(cb2 + 0) * 33 + b2] + bi2[u] + bf2f(zv.s[u * 4 + 0]);
            float zf = zb[(cb2 + 1) * 33 + b2] + bff[u] + bf2f(zv.s[u * 4 + 1]);
            float zc = zb[(cb2 + 2) * 33 + b2] + bc2[u] + bf2f(zv.s[u * 4 + 2]);
            float zo = zb[(cb2 + 3) * 33 + b2] + bo2[u] + bf2f(zv.s[u * 4 + 3]);
            float co = cst[u];
            float ig = sigm(zi + co * pI[u]);
            float fg = sigm(zf + co * pF[u]);
            float cn = fg * co + ig * fast_tanh(zc);
            float og = sigm(zo + cn * pO[u]);
            cst[u] = cn;
            hnew[u] = f2bf(og * fast_tanh(cn));
        }
        union { ushort s[2]; unsigned w; } hv;
        hv.s[0] = hnew[0]; hv.s[1] = hnew[1];
        __hip_atomic_store(
            (unsigned*)(h_hist + (size_t)(tl + 1) * (B_ * H_) + (size_t)gr * H_ + ub + seg * 2),
            hv.w, __ATOMIC_RELAXED, __HIP_MEMORY_SCOPE_AGENT);

        // publish: syncthreads drains the store's vmcnt for all waves, then flag my group
        __syncthreads();
        if (tid == 0)
            __hip_atomic_fetch_add(myFlag, 1u, __ATOMIC_RELAXED, __HIP_MEMORY_SCOPE_AGENT);
        if (tl < TC_ - 1) {
            if (tid < 8) {
                unsigned tgt = (unsigned)(SG + 1) * 4u;
                while (__hip_atomic_load(flags + tid * 16,
                           __ATOMIC_RELAXED, __HIP_MEMORY_SCOPE_AGENT) < tgt)
                    __builtin_amdgcn_s_sleep(1);
            }
            __syncthreads();
        }
    }
    *(float2*)(c_buf + (long)gr * H_ + ub + seg * 2) = *(float2*)cst;
}

// ---------------- final (per chunk): out = tanh(BN(h)) @ W_out  (N padded 10->16) ----------
// 64 blocks x 256 threads, 64 rows/block; wave i owns rows i*16..+15; K-order unchanged.
__global__ __launch_bounds__(256) void final_chunk(
    const ushort* __restrict__ h_hist, const ushort* __restrict__ woutT,
    const float* __restrict__ sc2, const float* __restrict__ sh2,
    float* __restrict__ out, int t0)
{
    __shared__ __align__(16) ushort As[64 * 40];
    __shared__ __align__(16) ushort Bs[16 * 40];
    int tid = threadIdx.x;
    long r0 = (long)blockIdx.x * 64;
    const ushort* hbase = h_hist + (long)B_ * H_ + r0 * H_;   // slot 1 onward
    int wave = tid >> 6, lane = tid & 63;
    int l15 = lane & 15, quad = lane >> 4;

    f32x4 acc = {0.f, 0.f, 0.f, 0.f};

    for (int kk = 0; kk < H_ / 32; ++kk) {
        int kb = kk * 32;
        {
            int row = tid >> 2, ch = tid & 3;          // 64 rows x 4 col-chunks = 256
            int k = kb + ch * 8;
            union { uint4 u4; ushort s[8]; } in, ov;
            in.u4 = *(const uint4*)(hbase + (long)row * H_ + k);
            float4 sa = *(const float4*)(sc2 + k), sb = *(const float4*)(sc2 + k + 4);
            float4 ba = *(const float4*)(sh2 + k), bb = *(const float4*)(sh2 + k + 4);
            ov.s[0] = f2bf(fast_tanh(bf2f(in.s[0]) * sa.x + ba.x));
            ov.s[1] = f2bf(fast_tanh(bf2f(in.s[1]) * sa.y + ba.y));
            ov.s[2] = f2bf(fast_tanh(bf2f(in.s[2]) * sa.z + ba.z));
            ov.s[3] = f2bf(fast_tanh(bf2f(in.s[3]) * sa.w + ba.w));
            ov.s[4] = f2bf(fast_tanh(bf2f(in.s[4]) * sb.x + bb.x));
            ov.s[5] = f2bf(fast_tanh(bf2f(in.s[5]) * sb.y + bb.y));
            ov.s[6] = f2bf(fast_tanh(bf2f(in.s[6]) * sb.z + bb.z));
            ov.s[7] = f2bf(fast_tanh(bf2f(in.s[7]) * sb.w + bb.w));
            *(uint4*)&As[row * 40 + ch * 8] = ov.u4;
        }
        if (tid < 64) {
            int row = tid >> 2, ch = tid & 3;
            *(uint4*)&Bs[row * 40 + ch * 8] = *(const uint4*)(woutT + row * H_ + kb + ch * 8);
        }
        __syncthreads();
        s16x8 bfr = *(const s16x8*)&Bs[l15 * 40 + quad * 8];
        s16x8 af  = *(const s16x8*)&As[(wave * 16 + l15) * 40 + quad * 8];
        acc = __builtin_amdgcn_mfma_f32_16x16x32_bf16(af, bfr, acc, 0, 0, 0);
        __syncthreads();
    }
    if (l15 < C_) {
        for (int r = 0; r < 4; r++) {
            long rg = r0 + wave * 16 + quad * 4 + r;  // = tl*B + b
            int tl = (int)(rg >> 8);
            int b  = (int)(rg & (B_ - 1));
            out[((long)b * T_ + t0 + tl) * C_ + l15] = acc[r];
        }
    }
}

extern "C" void kernel_launch(void* const* d_in, const int* in_sizes, int n_in,
                              void* d_out, int out_size, void* d_ws, size_t ws_size,
                              hipStream_t stream)
{
    const float* x       = (const float*)d_in[0];
    const float* W_fe    = (const float*)d_in[1];
    const float* b_fe    = (const float*)d_in[2];
    const float* gamma1  = (const float*)d_in[3];
    const float* beta1   = (const float*)d_in[4];
    const float* mean1   = (const float*)d_in[5];
    const float* var1    = (const float*)d_in[6];
    const float* kernelw = (const float*)d_in[7];
    const float* reck    = (const float*)d_in[8];
    const float* bias    = (const float*)d_in[9];
    const float* peep_i  = (const float*)d_in[10];
    const float* peep_f  = (const float*)d_in[11];
    const float* peep_o  = (const float*)d_in[12];
    const float* gamma2  = (const float*)d_in[13];
    const float* beta2   = (const float*)d_in[14];
    const float* mean2   = (const float*)d_in[15];
    const float* var2    = (const float*)d_in[16];
    const float* W_out   = (const float*)d_in[17];
    float* out = (float*)d_out;

    char* ws = (char*)d_ws;
    size_t o = 0;
    ushort* wfeT  = (ushort*)(ws + o); o += (size_t)H_ * FP_ * 2;              // 1.64 MB
    ushort* kT2   = (ushort*)(ws + o); o += (size_t)NG_ * H_ * 2;              // 8.39 MB
    ushort* rT2   = (ushort*)(ws + o); o += (size_t)NG_ * H_ * 2;              // 8.39 MB
    ushort* xbf_c = (ushort*)(ws + o); o += (size_t)MC_ * FP_ * 2;             // 6.55 MB
    ushort* feat_c= (ushort*)(ws + o); o += (size_t)MC_ * H_ * 2;              // 8.39 MB
    ushort* zx_c  = (ushort*)(ws + o); o += (size_t)MC_ * NG_ * 2;             // 33.55 MB
    ushort* h_hist= (ushort*)(ws + o); o += (size_t)(TC_ + 1) * B_ * H_ * 2;   // 8.91 MB
    float*  c_buf = (float*)(ws + o);  o += (size_t)B_ * H_ * 4;               // 1.05 MB
    float*  sc1   = (float*)(ws + o);  o += 4096;
    float*  sh1   = (float*)(ws + o);  o += 4096;
    float*  sc2   = (float*)(ws + o);  o += 4096;
    float*  sh2   = (float*)(ws + o);  o += 4096;
    ushort* woutT = (ushort*)(ws + o); o += 16 * H_ * 2;
    unsigned* bar = (unsigned*)(ws + o); o += 4096;
    // total ~77 MB

    prep_params<<<dim3(B_ * H_ / 256), dim3(256), 0, stream>>>(
        gamma1, beta1, mean1, var1, gamma2, beta2, mean2, var2, W_out,
        sc1, sh1, sc2, sh2, woutT, c_buf, h_hist, bar);

    transpose_f32_to_bf16<<<dim3(32, 25), dim3(256), 0, stream>>>(W_fe, wfeT, F_, H_, FP_);
    transpose_perm_bf16<<<dim3(128, 32), dim3(256), 0, stream>>>(kernelw, kT2);
    transpose_perm_bf16<<<dim3(128, 32), dim3(256), 0, stream>>>(reck, rT2);

    // prologue: convert(0) + gemm1(0)
    convert_x<<<dim3(MC_ * FP_ / 8 / 256), dim3(256), 0, stream>>>(x, xbf_c, 0);
    gemm1_c<<<dim3(512), dim3(256), 0, stream>>>(xbf_c, wfeT, b_fe, sc1, sh1, feat_c);

    for (int ci = 0; ci < T_ / TC_; ++ci) {
        int t0 = ci * TC_;
        int more = (ci < T_ / TC_ - 1) ? 1 : 0;
        gemm2_conv<<<dim3(1024 + MC_ * FP_ / 8 / 256), dim3(256), 0, stream>>>(
            feat_c, kT2, zx_c, x, xbf_c, t0 + TC_, more);
        lstm_g1<<<dim3(512), dim3(512), 0, stream>>>(
            h_hist, c_buf, rT2, zx_c, bias, peep_i, peep_f, peep_o, bar, ci,
            xbf_c, wfeT, b_fe, sc1, sh1, feat_c, more);
        final_chunk<<<dim3(MC_ / 64), dim3(256), 0, stream>>>(
            h_hist, woutT, sc2, sh2, out, t0);
    }
}

// Round 16
// 1792.349 us; speedup vs baseline: 1.1035x; 1.1035x over previous
//
#include <hip/hip_runtime.h>

#define B_ 256
#define T_ 128
#define F_ 784
#define FP_ 800          // F padded to multiple of 32
#define H_ 1024
#define NG_ 4096         // 4*H
#define C_ 10
#define TC_ 16           // time-chunk length
#define MC_ (B_ * TC_)   // rows per chunk = 4096
#define BN_EPS 1e-3f

typedef short s16x8 __attribute__((ext_vector_type(8)));
typedef float f32x4 __attribute__((ext_vector_type(4)));
typedef unsigned long long u64;

__device__ __forceinline__ ushort f2bf(float f) {
    union { float f; unsigned u; } v; v.f = f;
    unsigned r = v.u + 0x7FFFu + ((v.u >> 16) & 1u);
    return (ushort)(r >> 16);
}
__device__ __forceinline__ float bf2f(ushort h) {
    union { unsigned u; float f; } v; v.u = ((unsigned)h) << 16;
    return v.f;
}
__device__ __forceinline__ float sigm(float x) {
    return 1.0f / (1.0f + __expf(-x));
}
__device__ __forceinline__ float fast_tanh(float x) {
    x = fminf(15.0f, fmaxf(-15.0f, x));
    float e = __expf(2.0f * x);
    return (e - 1.0f) / (e + 1.0f);
}
// async 16B global -> LDS (DMA path, vmcnt-tracked)
__device__ __forceinline__ void gl_lds16(const ushort* g, ushort* l) {
    __builtin_amdgcn_global_load_lds(
        (__attribute__((address_space(1))) void*)(g),
        (__attribute__((address_space(3))) void*)(l), 16, 0, 0);
}

// ---------------- prep: BN scale/shift, W_out^T bf16, zero state, zero barriers ----------
__global__ __launch_bounds__(256) void prep_params(
    const float* __restrict__ gamma1, const float* __restrict__ beta1,
    const float* __restrict__ mean1, const float* __restrict__ var1,
    const float* __restrict__ gamma2, const float* __restrict__ beta2,
    const float* __restrict__ mean2, const float* __restrict__ var2,
    const float* __restrict__ W_out,
    float* __restrict__ sc1, float* __restrict__ sh1,
    float* __restrict__ sc2, float* __restrict__ sh2,
    ushort* __restrict__ woutT, float* __restrict__ c_buf, ushort* __restrict__ h_hist,
    unsigned* __restrict__ bar)
{
    int idx = blockIdx.x * 256 + threadIdx.x;
    if (idx < 1024) bar[idx] = 0u;
    if (idx < B_ * H_) { c_buf[idx] = 0.0f; h_hist[idx] = 0; }  // h slot 0 = h_{-1} = 0
    if (idx < H_) {
        float s1 = gamma1[idx] * rsqrtf(var1[idx] + BN_EPS);
        sc1[idx] = s1; sh1[idx] = beta1[idx] - mean1[idx] * s1;
        float s2 = gamma2[idx] * rsqrtf(var2[idx] + BN_EPS);
        sc2[idx] = s2; sh2[idx] = beta2[idx] - mean2[idx] * s2;
    }
    if (idx < 16 * H_) {
        int n = idx >> 10, k = idx & (H_ - 1);
        woutT[idx] = (n < C_) ? f2bf(W_out[k * C_ + n]) : (ushort)0;
    }
}

// ---------------- generic f32 (K,N) -> bf16 (N,Kpad) transpose, zero-padded ----------------
__global__ __launch_bounds__(256) void transpose_f32_to_bf16(
    const float* __restrict__ src, ushort* __restrict__ dst, int K, int N, int Kpad)
{
    __shared__ float tile[32][33];
    int tx = threadIdx.x & 31, ty = threadIdx.x >> 5;
    int bx = blockIdx.x, by = blockIdx.y;
    int col = bx * 32 + tx;
    for (int l = 0; l < 4; ++l) {
        int row = by * 32 + ty + l * 8;
        tile[ty + l * 8][tx] = (row < K && col < N) ? src[(long)row * N + col] : 0.0f;
    }
    __syncthreads();
    for (int l = 0; l < 4; ++l) {
        int n = bx * 32 + ty + l * 8;
        int k = by * 32 + tx;
        if (n < N && k < Kpad) dst[(long)n * Kpad + k] = f2bf(tile[tx][ty + l * 8]);
    }
}

// ---- same, but output rows gate-packed: src col n = g*H + u  ->  dst row n2 = u*4 + g ----
__global__ __launch_bounds__(256) void transpose_perm_bf16(
    const float* __restrict__ src, ushort* __restrict__ dst)   // K=H_, N=NG_, Kpad=H_
{
    __shared__ float tile[32][33];
    int tx = threadIdx.x & 31, ty = threadIdx.x >> 5;
    int bx = blockIdx.x, by = blockIdx.y;
    int col = bx * 32 + tx;
    for (int l = 0; l < 4; ++l) {
        int row = by * 32 + ty + l * 8;
        tile[ty + l * 8][tx] = (row < H_) ? src[(long)row * NG_ + col] : 0.0f;
    }
    __syncthreads();
    for (int l = 0; l < 4; ++l) {
        int n = bx * 32 + ty + l * 8;       // original col: g*H + u
        int k = by * 32 + tx;
        int n2 = (n & (H_ - 1)) * 4 + (n >> 10);
        dst[(long)n2 * H_ + k] = f2bf(tile[tx][ty + l * 8]);
    }
}

// ---------------- x chunk -> bf16, chunk-row order (tl*B+b), padded K to 800 ----------------
__device__ __forceinline__ void convert_body(
    const float* __restrict__ x, ushort* __restrict__ xbf, int t0, int idx)
{
    int m = idx / 100;
    int kc = idx - m * 100;
    int b = m & (B_ - 1), tl = m >> 8;
    int k = kc * 8;
    ushort o[8];
    if (k < F_) {
        const float* src = x + ((long)b * T_ + t0 + tl) * F_ + k;
        float4 v0 = *(const float4*)src, v1 = *(const float4*)(src + 4);
        o[0]=f2bf(v0.x); o[1]=f2bf(v0.y); o[2]=f2bf(v0.z); o[3]=f2bf(v0.w);
        o[4]=f2bf(v1.x); o[5]=f2bf(v1.y); o[6]=f2bf(v1.z); o[7]=f2bf(v1.w);
    } else {
        for (int i = 0; i < 8; ++i) o[i] = 0;
    }
    *(uint4*)(xbf + (long)m * FP_ + k) = *(uint4*)o;
}

__global__ __launch_bounds__(256) void convert_x(
    const float* __restrict__ x, ushort* __restrict__ xbf, int t0)
{
    convert_body(x, xbf, t0, blockIdx.x * 256 + threadIdx.x);
}

// ---------------- GEMM1 tile body: one 64x128 output tile, 256 threads (ltid) --------------
// v15-proven: staging via global_load_lds; per-output k-order fixed -> bitwise-same.
__device__ __forceinline__ void gemm1_tile(
    ushort* As, ushort* Bs, int ltid, int L,
    const ushort* __restrict__ xbf, const ushort* __restrict__ wfeT,
    const float* __restrict__ b_fe, const float* __restrict__ sc1, const float* __restrict__ sh1,
    ushort* __restrict__ feat_c)
{
    int m0 = (L >> 3) * 64;                   // m-tile (64 rows)
    int n0 = (L & 7) * 128;                   // n-tile (128 cols)
    int wave = ltid >> 6, lane = ltid & 63;
    int wm = wave >> 1, wn = wave & 1;        // 2 m-groups (32 rows) x 2 n-groups (64 cols)
    int l15 = lane & 15, quad = lane >> 4;

    f32x4 zero = {0.f, 0.f, 0.f, 0.f};
    f32x4 acc[2][4];
    for (int i = 0; i < 2; i++) for (int j = 0; j < 4; j++) acc[i][j] = zero;

    int srow = lane >> 2, kcol = (lane & 3) * 8;
    for (int kk = 0; kk < FP_ / 32; ++kk) {
        int kb = kk * 32;
        #pragma unroll
        for (int i = 0; i < 3; ++i) {
            int u = wave * 3 + i;                     // 0..11
            int cr = ((u < 4) ? (u << 4) : ((u - 4) << 4)) + srow;
            const ushort* src = (u < 4) ? (xbf  + (long)(m0 + cr) * FP_ + kb + kcol)
                                        : (wfeT + (long)(n0 + cr) * FP_ + kb + kcol);
            ushort* dst = (u < 4) ? (As + (u * 64 + lane) * 8)
                                  : (Bs + ((u - 4) * 64 + lane) * 8);
            gl_lds16(src, dst);
        }
        __syncthreads();
        s16x8 af[2], bfr[4];
        for (int i = 0; i < 2; i++) af[i]  = *(const s16x8*)&As[(wm * 32 + i * 16 + l15) * 32 + quad * 8];
        for (int j = 0; j < 4; j++) bfr[j] = *(const s16x8*)&Bs[(wn * 64 + j * 16 + l15) * 32 + quad * 8];
        for (int i = 0; i < 2; i++)
            for (int j = 0; j < 4; j++)
                acc[i][j] = __builtin_amdgcn_mfma_f32_16x16x32_bf16(af[i], bfr[j], acc[i][j], 0, 0, 0);
        __syncthreads();
    }
    for (int j = 0; j < 4; j++) {
        int n_g = n0 + wn * 64 + j * 16 + l15;
        float bia = b_fe[n_g], s1 = sc1[n_g], sh = sh1[n_g];
        for (int i = 0; i < 2; i++) {
            int mb = m0 + wm * 32 + i * 16 + quad * 4;
            for (int r = 0; r < 4; r++) {
                float v = fast_tanh(acc[i][j][r] + bia);
                v = fast_tanh(v * s1 + sh);
                feat_c[(long)(mb + r) * H_ + n_g] = f2bf(v);
            }
        }
    }
}

// standalone gemm1 (prologue, chunk 0): 512 blocks x 256 thr
__global__ __launch_bounds__(256, 2) void gemm1_c(
    const ushort* __restrict__ xbf, const ushort* __restrict__ wfeT,
    const float* __restrict__ b_fe, const float* __restrict__ sc1, const float* __restrict__ sh1,
    ushort* __restrict__ feat_c)
{
    __shared__ __align__(16) ushort As[64 * 32];
    __shared__ __align__(16) ushort Bs[128 * 32];
    int h = blockIdx.x;
    int L = (h & 7) * 64 + (h >> 3);          // [0,512)
    gemm1_tile(As, Bs, threadIdx.x, L, xbf, wfeT, b_fe, sc1, sh1, feat_c);
}

// ---------------- GEMM2 (per chunk) + fused convert_x(ci+1) -------------------------------
// gemm2 role: blocks 0..1023, supertile/XCD remap (R7-proven). convert role: blocks 1024+.
// R14-proven (no interference: gemm2 is throughput-bound at 4 blocks/CU).
__global__ __launch_bounds__(256) void gemm2_conv(
    const ushort* __restrict__ feat_c, const ushort* __restrict__ kT2,
    ushort* __restrict__ zx_c,
    const float* __restrict__ x, ushort* __restrict__ xbf, int t0n, int do_conv)
{
    int hb = blockIdx.x;
    int tid = threadIdx.x;
    if (hb >= 1024) {
        if (do_conv)
            convert_body(x, xbf, t0n, (hb - 1024) * 256 + tid);
        return;
    }
    __shared__ __align__(16) ushort As[128 * 32];
    __shared__ __align__(16) ushort Bs[128 * 32];
    int L = (hb & 7) * 128 + (hb >> 3);       // [0,1024)
    int st = L >> 6, s = L & 63;              // st in [0,16)
    int m0 = ((st >> 2) * 8 + (s >> 3)) * 128; // by in [0,32)
    int n0 = ((st & 3) * 8 + (s & 7)) * 128;   // bx in [0,32)
    int wave = tid >> 6, lane = tid & 63;
    int wm = wave >> 1, wn = wave & 1;
    int l15 = lane & 15, quad = lane >> 4;

    f32x4 zero = {0.f, 0.f, 0.f, 0.f};
    f32x4 acc[4][4];
    for (int i = 0; i < 4; i++) for (int j = 0; j < 4; j++) acc[i][j] = zero;

    int srow = lane >> 2, kcol = (lane & 3) * 8;
    for (int kk = 0; kk < H_ / 32; ++kk) {
        int kb = kk * 32;
        #pragma unroll
        for (int i = 0; i < 4; ++i) {
            int c = wave * 4 + i;
            int cr = ((c & 7) << 4) + srow;
            const ushort* src = (c < 8) ? (feat_c + (long)(m0 + cr) * H_ + kb + kcol)
                                        : (kT2   + (long)(n0 + cr) * H_ + kb + kcol);
            ushort* dst = ((c < 8) ? As : Bs) + ((c & 7) << 9) + lane * 8;
            gl_lds16(src, dst);
        }
        __syncthreads();
        s16x8 af[4], bfr[4];
        for (int i = 0; i < 4; i++) af[i]  = *(const s16x8*)&As[(wm * 64 + i * 16 + l15) * 32 + quad * 8];
        for (int j = 0; j < 4; j++) bfr[j] = *(const s16x8*)&Bs[(wn * 64 + j * 16 + l15) * 32 + quad * 8];
        for (int i = 0; i < 4; i++)
            for (int j = 0; j < 4; j++)
                acc[i][j] = __builtin_amdgcn_mfma_f32_16x16x32_bf16(af[i], bfr[j], acc[i][j], 0, 0, 0);
        __syncthreads();
    }
    for (int j = 0; j < 4; j++) {
        int n_g = n0 + wn * 64 + j * 16 + l15;
        for (int i = 0; i < 4; i++) {
            int mb = m0 + wm * 64 + i * 16 + quad * 4;
            for (int r = 0; r < 4; r++)
                zx_c[(long)(mb + r) * NG_ + n_g] = f2bf(acc[i][j][r]);
        }
    }
}

// ---------------- persistent LSTM chunk v14: whole-strip LDS, 4 quarter segments -----------
// R13-proven standalone at ~121 us. Runs ALONE (R14 showed co-residency on the recurrence
// critical path costs more than the overlap gains). Canary kernel: counters must match R13.
__global__ __launch_bounds__(512, 2) void lstm_chunk(
    ushort* __restrict__ h_hist, float* __restrict__ c_buf,
    const ushort* __restrict__ rT2, const ushort* __restrict__ zx_c,
    const float* __restrict__ bias, const float* __restrict__ pi,
    const float* __restrict__ pf, const float* __restrict__ po,
    unsigned* __restrict__ bar, int ci)
{
    __shared__ __align__(16) ushort Hb[4][32 * 256];   // 4 x 16384 B = whole strip
    __shared__ float zbuf[128][33];                    // 16896 B
    int tid = threadIdx.x;
    int dom = blockIdx.x & 7;            // batch-domain: rows dom*32 .. (one XCD)
    int nb  = blockIdx.x >> 3;           // 0..31 unit-block
    int ub  = nb * 32;                   // first hidden unit owned (32 units)
    int m0  = dom * 32;
    unsigned* flags  = bar + dom * 8 * 16;                 // 8 lines, 64B apart
    unsigned* myFlag = bar + (dom * 8 + (nb >> 2)) * 16;

    int wave = tid >> 6, lane = tid & 63;
    int wn = wave;                        // 8 n-groups (16 gate-cols each)
    int l15 = lane & 15, quad = lane >> 4;

    int b2 = tid & 31, seg = tid >> 5;   // cell identity: local row b2, units seg*2..seg*2+1
    int gr = m0 + b2;                    // global batch row
    float cst[2];
    *(float2*)cst = *(const float2*)(c_buf + (long)gr * H_ + ub + seg * 2);
    float bi2[2], bff[2], bc2[2], bo2[2], pI[2], pF[2], pO[2];
    for (int u = 0; u < 2; ++u) {
        int ug = ub + seg * 2 + u;
        bi2[u] = bias[ug];          bff[u] = bias[H_ + ug];
        bc2[u] = bias[2 * H_ + ug]; bo2[u] = bias[3 * H_ + ug];
        pI[u] = pi[ug]; pF[u] = pf[ug]; pO[u] = po[ug];
    }

    // R strip fragments -> registers (once per chunk). 128 VGPRs.
    s16x8 rfrag[32];
    {
        const ushort* rbase = rT2 + (long)(ub * 4 + wn * 16 + l15) * H_ + quad * 8;
        #pragma unroll
        for (int kk = 0; kk < 32; ++kk)
            rfrag[kk] = *(const s16x8*)(rbase + kk * 32);
    }

    // staging geometry: per quarter, thread issues 2 DMAs. instr i: granule G = i*512+tid:
    // row = G>>5 (0..31), colg = G&31. Source colg pre-swizzled ^ (row&7).
    int srcoff[2], ldsoff[2];
    #pragma unroll
    for (int i = 0; i < 2; ++i) {
        int G  = i * 512 + tid;
        int sr = G >> 5;                              // 0..31
        int sc = (G & 31) ^ (sr & 7);
        srcoff[i] = sr * H_ + sc * 8;                 // ushort offset; + q*256 per quarter
        ldsoff[i] = G * 8;
    }

    // MFMA-read geometry: de-swizzle on read with the same XOR
    int r0 = l15;
    int rx = l15 & 7;                                 // (r0+16)&7 == rx
    asm volatile("s_waitcnt vmcnt(0)" ::: "memory");
    __syncthreads();

    for (int tl = 0; tl < TC_; ++tl) {
        int SG = ci * TC_ + tl;
        const ushort* hsrc = h_hist +
            (size_t)((tl == 0) ? (ci == 0 ? 0 : TC_) : tl) * (B_ * H_) + (size_t)m0 * H_;
        const ushort* zr = zx_c + ((size_t)tl * B_ + gr) * NG_ + (ub + seg * 2) * 4;
        union { uint4 u4; ushort s[8]; } zv;

        // prologue issue order (pinned): zx first, then Q0..Q3 (2 instr each) = 9 outstanding
        zv.u4 = *(const uint4*)zr;
        __builtin_amdgcn_sched_barrier(0);
        #pragma unroll
        for (int q = 0; q < 4; ++q) {
            #pragma unroll
            for (int i = 0; i < 2; ++i)
                gl_lds16(hsrc + srcoff[i] + q * 256, &Hb[q][0] + ldsoff[i]);
            __builtin_amdgcn_sched_barrier(0);
        }

        f32x4 acc0 = {0.f, 0.f, 0.f, 0.f}, acc1 = {0.f, 0.f, 0.f, 0.f};

        // segment E (K=256): wait(VN)+barrier ; 8 x (2 ds_read_b128 + 2 MFMA)
#define SEG(E, VN) \
        asm volatile("s_waitcnt vmcnt(" #VN ") lgkmcnt(0)\n\ts_barrier" ::: "memory"); \
        __builtin_amdgcn_sched_barrier(0); \
        { \
            const ushort* bp = &Hb[E][0]; \
            _Pragma("unroll") \
            for (int kkl = 0; kkl < 8; ++kkl) { \
                s16x8 bfr = rfrag[(E) * 8 + kkl]; \
                int po_ = ((kkl * 4 + quad) ^ rx) << 3; \
                s16x8 a0v = *(const s16x8*)(bp + r0 * 256 + po_); \
                s16x8 a1v = *(const s16x8*)(bp + (r0 + 16) * 256 + po_); \
                acc0 = __builtin_amdgcn_mfma_f32_16x16x32_bf16(a0v, bfr, acc0, 0, 0, 0); \
                acc1 = __builtin_amdgcn_mfma_f32_16x16x32_bf16(a1v, bfr, acc1, 0, 0, 0); \
            } \
        }

        SEG(0, 6)
        SEG(1, 4)
        SEG(2, 2)
        SEG(3, 0)
#undef SEG

        // z -> LDS, col-major: zbuf[local gatecol][local row]
        #pragma unroll
        for (int r = 0; r < 4; ++r)
            zbuf[wn * 16 + l15][quad * 4 + r] = acc0[r];
        #pragma unroll
        for (int r = 0; r < 4; ++r)
            zbuf[wn * 16 + l15][16 + quad * 4 + r] = acc1[r];
        __syncthreads();

        // cell update: 2 units/thread; zx gate-packed -> one contiguous 16B read
        ushort hnew[2];
        #pragma unroll
        for (int u = 0; u < 2; ++u) {
            int cb2 = (seg * 2 + u) * 4;
            float zi = zbuf[cb2 + 0][b2] + bi2[u] + bf2f(zv.s[u * 4 + 0]);
            float zf = zbuf[cb2 + 1][b2] + bff[u] + bf2f(zv.s[u * 4 + 1]);
            float zc = zbuf[cb2 + 2][b2] + bc2[u] + bf2f(zv.s[u * 4 + 2]);
            float zo = zbuf[cb2 + 3][b2] + bo2[u] + bf2f(zv.s[u * 4 + 3]);
            float co = cst[u];
            float ig = sigm(zi + co * pI[u]);
            float fg = sigm(zf + co * pF[u]);
            float cn = fg * co + ig * fast_tanh(zc);
            float og = sigm(zo + cn * pO[u]);
            cst[u] = cn;
            hnew[u] = f2bf(og * fast_tanh(cn));
        }
        union { ushort s[2]; unsigned w; } hv;
        hv.s[0] = hnew[0]; hv.s[1] = hnew[1];
        __hip_atomic_store(
            (unsigned*)(h_hist + (size_t)(tl + 1) * (B_ * H_) + (size_t)gr * H_ + ub + seg * 2),
            hv.w, __ATOMIC_RELAXED, __HIP_MEMORY_SCOPE_AGENT);

        // publish: syncthreads drains the store's vmcnt for all waves, then flag my group
        __syncthreads();
        if (tid == 0)
            __hip_atomic_fetch_add(myFlag, 1u, __ATOMIC_RELAXED, __HIP_MEMORY_SCOPE_AGENT);
        if (tl < TC_ - 1) {
            if (tid < 8) {
                unsigned tgt = (unsigned)(SG + 1) * 4u;
                while (__hip_atomic_load(flags + tid * 16,
                           __ATOMIC_RELAXED, __HIP_MEMORY_SCOPE_AGENT) < tgt)
                    __builtin_amdgcn_s_sleep(1);
            }
            __syncthreads();
        }
    }
    *(float2*)(c_buf + (long)gr * H_ + ub + seg * 2) = *(float2*)cst;
}

// ------- fused: final(ci) [blocks 0..63] + gemm1(ci+1) [blocks 64..575] --------------------
// final: 64 rows/block x 256 thr (R14-proven body). gemm1: one 64x128 tile/block (R13-proven
// body). Disjoint data: final reads h_hist/woutT -> out; gemm1 reads xbf(ci+1) (written two
// dispatches earlier in gemm2_conv) -> feat_c (read next dispatch). No intra-dispatch deps.
__global__ __launch_bounds__(256) void final_g1(
    const ushort* __restrict__ h_hist, const ushort* __restrict__ woutT,
    const float* __restrict__ sc2, const float* __restrict__ sh2,
    float* __restrict__ out, int t0,
    const ushort* __restrict__ xbf, const ushort* __restrict__ wfeT,
    const float* __restrict__ b_fe, const float* __restrict__ sc1,
    const float* __restrict__ sh1, ushort* __restrict__ feat_c, int do_g1)
{
    __shared__ __align__(16) ushort smem[6144];       // 12288 B (max of both roles)
    int hb = blockIdx.x;
    int tid = threadIdx.x;
    if (hb >= 64) {
        if (do_g1) {
            int b = hb - 64;                          // 0..511
            int L = (b & 7) * 64 + (b >> 3);          // bijective onto [0,512)
            gemm1_tile(smem, smem + 2048, tid, L, xbf, wfeT, b_fe, sc1, sh1, feat_c);
        }
        return;
    }
    ushort* As = smem;                                // 64*40 = 2560 ushorts
    ushort* Bs = smem + 2560;                         // 16*40 = 640 ushorts
    long r0 = (long)hb * 64;
    const ushort* hbase = h_hist + (long)B_ * H_ + r0 * H_;   // slot 1 onward
    int wave = tid >> 6, lane = tid & 63;
    int l15 = lane & 15, quad = lane >> 4;

    f32x4 acc = {0.f, 0.f, 0.f, 0.f};

    for (int kk = 0; kk < H_ / 32; ++kk) {
        int kb = kk * 32;
        {
            int row = tid >> 2, ch = tid & 3;          // 64 rows x 4 col-chunks = 256
            int k = kb + ch * 8;
            union { uint4 u4; ushort s[8]; } in, ov;
            in.u4 = *(const uint4*)(hbase + (long)row * H_ + k);
            float4 sa = *(const float4*)(sc2 + k), sb = *(const float4*)(sc2 + k + 4);
            float4 ba = *(const float4*)(sh2 + k), bb = *(const float4*)(sh2 + k + 4);
            ov.s[0] = f2bf(fast_tanh(bf2f(in.s[0]) * sa.x + ba.x));
            ov.s[1] = f2bf(fast_tanh(bf2f(in.s[1]) * sa.y + ba.y));
            ov.s[2] = f2bf(fast_tanh(bf2f(in.s[2]) * sa.z + ba.z));
            ov.s[3] = f2bf(fast_tanh(bf2f(in.s[3]) * sa.w + ba.w));
            ov.s[4] = f2bf(fast_tanh(bf2f(in.s[4]) * sb.x + bb.x));
            ov.s[5] = f2bf(fast_tanh(bf2f(in.s[5]) * sb.y + bb.y));
            ov.s[6] = f2bf(fast_tanh(bf2f(in.s[6]) * sb.z + bb.z));
            ov.s[7] = f2bf(fast_tanh(bf2f(in.s[7]) * sb.w + bb.w));
            *(uint4*)&As[row * 40 + ch * 8] = ov.u4;
        }
        if (tid < 64) {
            int row = tid >> 2, ch = tid & 3;
            *(uint4*)&Bs[row * 40 + ch * 8] = *(const uint4*)(woutT + row * H_ + kb + ch * 8);
        }
        __syncthreads();
        s16x8 bfr = *(const s16x8*)&Bs[l15 * 40 + quad * 8];
        s16x8 af  = *(const s16x8*)&As[(wave * 16 + l15) * 40 + quad * 8];
        acc = __builtin_amdgcn_mfma_f32_16x16x32_bf16(af, bfr, acc, 0, 0, 0);
        __syncthreads();
    }
    if (l15 < C_) {
        for (int r = 0; r < 4; r++) {
            long rg = r0 + wave * 16 + quad * 4 + r;  // = tl*B + b
            int tl = (int)(rg >> 8);
            int b  = (int)(rg & (B_ - 1));
            out[((long)b * T_ + t0 + tl) * C_ + l15] = acc[r];
        }
    }
}

extern "C" void kernel_launch(void* const* d_in, const int* in_sizes, int n_in,
                              void* d_out, int out_size, void* d_ws, size_t ws_size,
                              hipStream_t stream)
{
    const float* x       = (const float*)d_in[0];
    const float* W_fe    = (const float*)d_in[1];
    const float* b_fe    = (const float*)d_in[2];
    const float* gamma1  = (const float*)d_in[3];
    const float* beta1   = (const float*)d_in[4];
    const float* mean1   = (const float*)d_in[5];
    const float* var1    = (const float*)d_in[6];
    const float* kernelw = (const float*)d_in[7];
    const float* reck    = (const float*)d_in[8];
    const float* bias    = (const float*)d_in[9];
    const float* peep_i  = (const float*)d_in[10];
    const float* peep_f  = (const float*)d_in[11];
    const float* peep_o  = (const float*)d_in[12];
    const float* gamma2  = (const float*)d_in[13];
    const float* beta2   = (const float*)d_in[14];
    const float* mean2   = (const float*)d_in[15];
    const float* var2    = (const float*)d_in[16];
    const float* W_out   = (const float*)d_in[17];
    float* out = (float*)d_out;

    char* ws = (char*)d_ws;
    size_t o = 0;
    ushort* wfeT  = (ushort*)(ws + o); o += (size_t)H_ * FP_ * 2;              // 1.64 MB
    ushort* kT2   = (ushort*)(ws + o); o += (size_t)NG_ * H_ * 2;              // 8.39 MB
    ushort* rT2   = (ushort*)(ws + o); o += (size_t)NG_ * H_ * 2;              // 8.39 MB
    ushort* xbf_c = (ushort*)(ws + o); o += (size_t)MC_ * FP_ * 2;             // 6.55 MB
    ushort* feat_c= (ushort*)(ws + o); o += (size_t)MC_ * H_ * 2;              // 8.39 MB
    ushort* zx_c  = (ushort*)(ws + o); o += (size_t)MC_ * NG_ * 2;             // 33.55 MB
    ushort* h_hist= (ushort*)(ws + o); o += (size_t)(TC_ + 1) * B_ * H_ * 2;   // 8.91 MB
    float*  c_buf = (float*)(ws + o);  o += (size_t)B_ * H_ * 4;               // 1.05 MB
    float*  sc1   = (float*)(ws + o);  o += 4096;
    float*  sh1   = (float*)(ws + o);  o += 4096;
    float*  sc2   = (float*)(ws + o);  o += 4096;
    float*  sh2   = (float*)(ws + o);  o += 4096;
    ushort* woutT = (ushort*)(ws + o); o += 16 * H_ * 2;
    unsigned* bar = (unsigned*)(ws + o); o += 4096;
    // total ~77 MB

    prep_params<<<dim3(B_ * H_ / 256), dim3(256), 0, stream>>>(
        gamma1, beta1, mean1, var1, gamma2, beta2, mean2, var2, W_out,
        sc1, sh1, sc2, sh2, woutT, c_buf, h_hist, bar);

    transpose_f32_to_bf16<<<dim3(32, 25), dim3(256), 0, stream>>>(W_fe, wfeT, F_, H_, FP_);
    transpose_perm_bf16<<<dim3(128, 32), dim3(256), 0, stream>>>(kernelw, kT2);
    transpose_perm_bf16<<<dim3(128, 32), dim3(256), 0, stream>>>(reck, rT2);

    // prologue: convert(0) + gemm1(0)
    convert_x<<<dim3(MC_ * FP_ / 8 / 256), dim3(256), 0, stream>>>(x, xbf_c, 0);
    gemm1_c<<<dim3(512), dim3(256), 0, stream>>>(xbf_c, wfeT, b_fe, sc1, sh1, feat_c);

    for (int ci = 0; ci < T_ / TC_; ++ci) {
        int t0 = ci * TC_;
        int more = (ci < T_ / TC_ - 1) ? 1 : 0;
        gemm2_conv<<<dim3(1024 + MC_ * FP_ / 8 / 256), dim3(256), 0, stream>>>(
            feat_c, kT2, zx_c, x, xbf_c, t0 + TC_, more);
        lstm_chunk<<<dim3(256), dim3(512), 0, stream>>>(
            h_hist, c_buf, rT2, zx_c, bias, peep_i, peep_f, peep_o, bar, ci);
        final_g1<<<dim3(64 + 512), dim3(256), 0, stream>>>(
            h_hist, woutT, sc2, sh2, out, t0,
            xbf_c, wfeT, b_fe, sc1, sh1, feat_c, more);
    }
}